// Round 4
// baseline (571.751 us; speedup 1.0000x reference)
//
#include <hip/hip_runtime.h>
#include <hip/hip_bf16.h>

typedef __attribute__((ext_vector_type(8))) short bf16x8; // 8 bf16 in 4 VGPRs
typedef __attribute__((ext_vector_type(4))) float f32x4;

#define MFMA16(a, b, c) __builtin_amdgcn_mfma_f32_16x16x32_bf16(a, b, c, 0, 0, 0)

static constexpr int S  = 4096;
static constexpr int Dm = 512;
static constexpr int Hh = 256;
static constexpr int Bb = 4;

// Swizzled LDS index helpers (bf16 units; 16B slot granularity).
__device__ __forceinline__ int kidx(int r, int c) { return r * 256 + (c ^ ((r & 7) << 3)); }
__device__ __forceinline__ int vidx(int r, int c) { return r * 64  + (c ^ ((r & 7) << 3)); }
__device__ __forceinline__ int pidx(int r, int c) { return r * 64  + (c ^ ((r & 7) << 3)); }

// ---------------------------------------------------------------------------
// Projection GEMM with depth-1 register prefetch + LDS double-buffer (R3, kept).
// ---------------------------------------------------------------------------
__global__ __launch_bounds__(256) void proj_kernel(
    const float* __restrict__ X,
    const float* __restrict__ W,
    const float* __restrict__ bias,
    __hip_bfloat16* __restrict__ out,
    int N, float scale, int transpose_out)
{
    __shared__ __hip_bfloat16 a_lds[2][64][32];
    __shared__ __hip_bfloat16 w_lds[2][64][32];

    const int tid  = threadIdx.x;
    const int lane = tid & 63;
    const int wave = tid >> 6;
    const int lr   = lane & 15;
    const int lg   = lane >> 4;
    const int m0   = blockIdx.y * 64;
    const int n0   = blockIdx.x * 64;

    const int arow = tid >> 2, aoff = (tid & 3) * 8;
    const int wkk  = tid >> 3, wnoff = (tid & 7) * 8;
    const float* asrc = X + (size_t)(m0 + arow) * 512 + aoff;
    const float* wsrc = W + (size_t)wkk * N + n0 + wnoff;

    f32x4 acc[4];
    #pragma unroll
    for (int n = 0; n < 4; ++n) acc[n] = (f32x4){0.f, 0.f, 0.f, 0.f};

    {
        float ar[8], wr[8];
        #pragma unroll
        for (int j = 0; j < 8; ++j) { ar[j] = asrc[j]; wr[j] = wsrc[j]; }
        #pragma unroll
        for (int j = 0; j < 8; ++j) a_lds[0][arow][aoff + j] = __float2bfloat16(ar[j]);
        #pragma unroll
        for (int j = 0; j < 8; ++j) w_lds[0][wnoff + j][wkk] = __float2bfloat16(wr[j]);
    }
    __syncthreads();

    int cur = 0;
    for (int k0 = 0; k0 < 512; k0 += 32) {
        float ar[8], wr[8];
        if (k0 < 480) {
            #pragma unroll
            for (int j = 0; j < 8; ++j) ar[j] = asrc[k0 + 32 + j];
            #pragma unroll
            for (int j = 0; j < 8; ++j) wr[j] = wsrc[(size_t)(k0 + 32) * N + j];
        }
        bf16x8 af = *(const bf16x8*)&a_lds[cur][wave * 16 + lr][lg * 8];
        __builtin_amdgcn_s_setprio(1);
        #pragma unroll
        for (int n = 0; n < 4; ++n) {
            bf16x8 bfr = *(const bf16x8*)&w_lds[cur][n * 16 + lr][lg * 8];
            acc[n] = MFMA16(af, bfr, acc[n]);
        }
        __builtin_amdgcn_s_setprio(0);
        if (k0 < 480) {
            #pragma unroll
            for (int j = 0; j < 8; ++j) a_lds[cur ^ 1][arow][aoff + j] = __float2bfloat16(ar[j]);
            #pragma unroll
            for (int j = 0; j < 8; ++j) w_lds[cur ^ 1][wnoff + j][wkk] = __float2bfloat16(wr[j]);
        }
        __syncthreads();
        cur ^= 1;
    }

    #pragma unroll
    for (int n = 0; n < 4; ++n) {
        int col = n0 + n * 16 + lr;
        float bia = bias[col];
        #pragma unroll
        for (int r = 0; r < 4; ++r) {
            int row = m0 + wave * 16 + lg * 4 + r;
            float val = (acc[n][r] + bia) * scale;
            if (!transpose_out) {
                out[(size_t)row * N + col] = __float2bfloat16(val);
            } else {
                int bidx = row >> 12, s = row & 4095;
                out[((size_t)bidx * N + col) * S + s] = __float2bfloat16(val);
            }
        }
    }
}

// ---------------------------------------------------------------------------
// score_kernel: QK^T -> exp(s) fp32 into attn buffer + partial row sums.
// Grid (S/64, 2, B) = 512 blocks: x = 64-q-row block, y = kv-half (32 kt each).
// 512 threads / 8 waves: wave (qg = w>>1) owns q-rows 16qg..+16,
// (half = w&1) owns kv-cols 32*half..+32 of each 64-col kt tile.
// ---------------------------------------------------------------------------
__global__ __launch_bounds__(512) void score_kernel(
    const __hip_bfloat16* __restrict__ Q,   // [B][S][H], 1/sqrt(H) pre-applied
    const __hip_bfloat16* __restrict__ K,   // [B][S][H]
    float* __restrict__ attn,               // [B][S][S] <- exp(s), unnormalized
    float* __restrict__ l_ws)               // [B][S][2] partial row sums
{
    __shared__ __hip_bfloat16 k_lds[64 * 256];  // 32 KB (swizzled)
    __shared__ float stats_lds[2][4][16];

    const int tid  = threadIdx.x;
    const int lane = tid & 63;
    const int w    = tid >> 6;
    const int lr   = lane & 15;
    const int lg   = lane >> 4;
    const int qg   = w >> 1;
    const int half = w & 1;
    const int b    = blockIdx.z;
    const int kvh  = blockIdx.y;
    const int q0   = blockIdx.x * 64;
    const int kt0  = kvh * 32;

    const __hip_bfloat16* Qb = Q + ((size_t)b * S + q0) * Hh;
    const __hip_bfloat16* Kb = K + (size_t)b * S * Hh;

    const int krow = tid >> 3, kcb = (tid & 7) * 8;

    bf16x8 qf[8];
    #pragma unroll
    for (int h = 0; h < 8; ++h)
        qf[h] = *(const bf16x8*)&Qb[(size_t)(qg * 16 + lr) * Hh + h * 32 + lg * 8];

    float lsum[4] = {0.f, 0.f, 0.f, 0.f};

    for (int kt = kt0; kt < kt0 + 32; ++kt) {
        // issue K loads early (overlap previous iteration's compute/stores)
        uint4 kr[4];
        const __hip_bfloat16* src = Kb + (size_t)(kt * 64 + krow) * Hh + kcb;
        #pragma unroll
        for (int c0 = 0; c0 < 4; ++c0) kr[c0] = *(const uint4*)&src[c0 * 64];
        __syncthreads();  // previous tile's readers done
        #pragma unroll
        for (int c0 = 0; c0 < 4; ++c0)
            *(uint4*)&k_lds[kidx(krow, kcb + c0 * 64)] = kr[c0];
        __syncthreads();

        f32x4 acc[2];
        #pragma unroll
        for (int nn = 0; nn < 2; ++nn) acc[nn] = (f32x4){0.f, 0.f, 0.f, 0.f};
        __builtin_amdgcn_s_setprio(1);
        #pragma unroll
        for (int nn = 0; nn < 2; ++nn) {
            int n = half * 2 + nn;
            #pragma unroll
            for (int h = 0; h < 8; ++h) {
                bf16x8 kf = *(const bf16x8*)&k_lds[kidx(n * 16 + lr, h * 32 + lg * 8)];
                acc[nn] = MFMA16(qf[h], kf, acc[nn]);
            }
        }
        __builtin_amdgcn_s_setprio(0);

        #pragma unroll
        for (int nn = 0; nn < 2; ++nn)
            #pragma unroll
            for (int r = 0; r < 4; ++r) {
                float e = __expf(acc[nn][r]);
                lsum[r] += e;
                int row_l = qg * 16 + lg * 4 + r;
                int col_l = (half * 2 + nn) * 16 + lr;
                attn[((size_t)(b * S + q0 + row_l)) * S + kt * 64 + col_l] = e;
            }
    }

    // reduce lsum across 16 lr lanes, merge the two col-halves, store partial l
    #pragma unroll
    for (int r = 0; r < 4; ++r)
        #pragma unroll
        for (int m = 1; m < 16; m <<= 1) lsum[r] += __shfl_xor(lsum[r], m);
    if (lr == 0) {
        #pragma unroll
        for (int r = 0; r < 4; ++r) stats_lds[half][qg][lg * 4 + r] = lsum[r];
    }
    __syncthreads();
    if (half == 0 && lr == 0) {
        #pragma unroll
        for (int r = 0; r < 4; ++r) {
            int row = q0 + qg * 16 + lg * 4 + r;
            l_ws[((size_t)(b * S + row)) * 2 + kvh] =
                lsum[r] + stats_lds[1][qg][lg * 4 + r];
        }
    }
}

// ---------------------------------------------------------------------------
// pv_kernel: read exp back, normalize + fmf, rewrite attn, PV MFMA.
// Grid (S/32, B) = 512 blocks: 32 q-rows per block, all 64 kt.
// 512 threads / 8 waves: wave w owns d-slice [64w, 64w+64).
// ---------------------------------------------------------------------------
__global__ __launch_bounds__(512) void pv_kernel(
    const __hip_bfloat16* __restrict__ VT,  // [B][D][S]
    const float* __restrict__ l_ws,         // [B][S][2]
    float* __restrict__ attn,               // in: exp(s); out: fmf(softmax)
    float* __restrict__ out)                // [B][S][D]
{
    __shared__ __hip_bfloat16 vt_lds[512 * 64];  // 64 KB (swizzled)
    __shared__ __hip_bfloat16 p_lds[32 * 64];    // 4 KB  (swizzled)

    const int tid  = threadIdx.x;
    const int lane = tid & 63;
    const int w    = tid >> 6;
    const int lr   = lane & 15;
    const int lg   = lane >> 4;
    const int b    = blockIdx.y;
    const int q0   = blockIdx.x * 32;

    const __hip_bfloat16* VTb = VT + (size_t)b * Dm * S;

    // exp/f lanes: 16 threads per row, 4 cols each
    const int erow = tid >> 4, ec4 = (tid & 15) * 4;
    float2 lp = *(const float2*)&l_ws[((size_t)(b * S + q0 + erow)) * 2];
    const float invl = 1.0f / (lp.x + lp.y);
    float* arow = attn + ((size_t)(b * S + q0 + erow)) * S;

    const int vrb = tid >> 3, vcb = (tid & 7) * 8;

    f32x4 oacc[2][4];
    #pragma unroll
    for (int qt = 0; qt < 2; ++qt)
        #pragma unroll
        for (int dt = 0; dt < 4; ++dt) oacc[qt][dt] = (f32x4){0.f, 0.f, 0.f, 0.f};

    for (int kt = 0; kt < 64; ++kt) {
        // issue exp load early (overlaps previous PV)
        float4 ev = *(const float4*)&arow[kt * 64 + ec4];
        __syncthreads();  // PV(kt-1) done -> vt_lds/p_lds free

        // stage VT tile (direct global->LDS copy, swizzled)
        #pragma unroll
        for (int j = 0; j < 8; ++j)
            *(uint4*)&vt_lds[vidx(j * 64 + vrb, vcb)] =
                *(const uint4*)&VTb[(size_t)(j * 64 + vrb) * S + kt * 64 + vcb];

        // normalize + fuzzy clamp; rewrite attn; stash bf16 P
        float p0 = ev.x * invl, p1 = ev.y * invl, p2 = ev.z * invl, p3 = ev.w * invl;
        float f0 = fmaxf(fminf(p0, 1.0f - p0) * (1.0f / 0.3f), 0.0f);
        float f1 = fmaxf(fminf(p1, 1.0f - p1) * (1.0f / 0.3f), 0.0f);
        float f2 = fmaxf(fminf(p2, 1.0f - p2) * (1.0f / 0.3f), 0.0f);
        float f3 = fmaxf(fminf(p3, 1.0f - p3) * (1.0f / 0.3f), 0.0f);
        *(float4*)&arow[kt * 64 + ec4] = make_float4(f0, f1, f2, f3);
        __hip_bfloat16 hb[4];
        hb[0] = __float2bfloat16(f0); hb[1] = __float2bfloat16(f1);
        hb[2] = __float2bfloat16(f2); hb[3] = __float2bfloat16(f3);
        *(uint2*)&p_lds[pidx(erow, ec4)] = *(const uint2*)hb;
        __syncthreads();  // p_lds + vt_lds visible

        // PV: wave w owns d-slice [64w, 64w+64)
        bf16x8 pf[2][2];
        #pragma unroll
        for (int qt = 0; qt < 2; ++qt)
            #pragma unroll
            for (int ks = 0; ks < 2; ++ks)
                pf[qt][ks] = *(const bf16x8*)&p_lds[pidx(qt * 16 + lr, ks * 32 + lg * 8)];
        __builtin_amdgcn_s_setprio(1);
        #pragma unroll
        for (int dt = 0; dt < 4; ++dt)
            #pragma unroll
            for (int ks = 0; ks < 2; ++ks) {
                bf16x8 vf = *(const bf16x8*)&vt_lds[vidx(w * 64 + dt * 16 + lr, ks * 32 + lg * 8)];
                #pragma unroll
                for (int qt = 0; qt < 2; ++qt)
                    oacc[qt][dt] = MFMA16(pf[qt][ks], vf, oacc[qt][dt]);
            }
        __builtin_amdgcn_s_setprio(0);
    }

    // epilogue: out[B][S][D] fp32
    #pragma unroll
    for (int qt = 0; qt < 2; ++qt)
        #pragma unroll
        for (int dt = 0; dt < 4; ++dt)
            #pragma unroll
            for (int r = 0; r < 4; ++r) {
                int row = q0 + qt * 16 + lg * 4 + r;
                out[((size_t)(b * S + row)) * Dm + w * 64 + dt * 16 + lr] = oacc[qt][dt][r];
            }
}

// ---------------------------------------------------------------------------
extern "C" void kernel_launch(void* const* d_in, const int* in_sizes, int n_in,
                              void* d_out, int out_size, void* d_ws, size_t ws_size,
                              hipStream_t stream) {
    const float* x  = (const float*)d_in[0];
    const float* Wq = (const float*)d_in[1];
    const float* bq = (const float*)d_in[2];
    const float* Wk = (const float*)d_in[3];
    const float* bk = (const float*)d_in[4];
    const float* Wv = (const float*)d_in[5];
    const float* bv = (const float*)d_in[6];

    float* out  = (float*)d_out;                      // [4,4096,512]
    float* attn = out + (size_t)Bb * S * Dm;          // [4,4096,4096]

    __hip_bfloat16* q_ws  = (__hip_bfloat16*)d_ws;              // [B][S][H]  8MB
    __hip_bfloat16* k_ws  = q_ws + (size_t)Bb * S * Hh;         // [B][S][H]  8MB
    __hip_bfloat16* vt_ws = k_ws + (size_t)Bb * S * Hh;         // [B][D][S] 16MB
    float*          l_ws  = (float*)(vt_ws + (size_t)Bb * Dm * S); // [B][S][2] 128KB

    const float scale = 0.0625f;  // 1/sqrt(256)

    proj_kernel<<<dim3(Hh / 64, (Bb * S) / 64), 256, 0, stream>>>(x, Wq, bq, q_ws, Hh, scale, 0);
    proj_kernel<<<dim3(Hh / 64, (Bb * S) / 64), 256, 0, stream>>>(x, Wk, bk, k_ws, Hh, 1.0f, 0);
    proj_kernel<<<dim3(Dm / 64, (Bb * S) / 64), 256, 0, stream>>>(x, Wv, bv, vt_ws, Dm, 1.0f, 1);

    score_kernel<<<dim3(S / 64, 2, Bb), 512, 0, stream>>>(q_ws, k_ws, attn, l_ws);
    pv_kernel<<<dim3(S / 32, Bb), 512, 0, stream>>>(vt_ws, l_ws, attn, out);
}